// Round 6
// baseline (338.211 us; speedup 1.0000x reference)
//
#include <hip/hip_runtime.h>
#include <hip/hip_bf16.h>

#define D_DIM 512
#define NROWS 256
#define NT 16
#define KSTEPS 16
#define S_SCALE 64.0f
#define COS_M 0.9210609940028851f
#define SIN_M 0.3894183423086505f

typedef short short8 __attribute__((ext_vector_type(8)));
typedef float f32x4 __attribute__((ext_vector_type(4)));

typedef const __attribute__((address_space(1))) void* gas1_t;
typedef __attribute__((address_space(3))) void* las3_t;

static __device__ __forceinline__ void gload16(const void* g, void* l){
  __builtin_amdgcn_global_load_lds((gas1_t)g, (las3_t)l, 16, 0, 0);
}

static __device__ __forceinline__ short f2bf(float f){
  __hip_bfloat16 h = __float2bfloat16(f);
  return __builtin_bit_cast(short, h);
}

// ---- emb = l2norm(x, 1e-5); also pack A-fragments (bf16, fragment-major) ----
__global__ void k_emb(const float* __restrict__ x, float* __restrict__ emb,
                      short* __restrict__ embA){
  int b = blockIdx.x, t = threadIdx.x;            // 256 blocks x 256 threads
  float v0 = x[b*D_DIM + t];
  float v1 = x[b*D_DIM + 256 + t];
  __shared__ float red[256];
  red[t] = v0*v0 + v1*v1;
  __syncthreads();
  for (int o=128;o>0;o>>=1){ if(t<o) red[t]+=red[t+o]; __syncthreads(); }
  float inv = 1.0f / fmaxf(sqrtf(red[0]), 1e-5f);
  float e0 = v0*inv, e1 = v1*inv;
  emb[b*D_DIM + t]       = e0;
  emb[b*D_DIM + 256 + t] = e1;
  int rb = b >> 4;
  {
    int d=t; int ks=d>>5, kg=(d>>3)&3, j=d&7;
    int lane=(kg<<4)|(b&15);
    embA[((ks*16+rb)*64+lane)*8+j] = f2bf(e0);
  }
  {
    int d=t+256; int ks=d>>5, kg=(d>>3)&3, j=d&7;
    int lane=(kg<<4)|(b&15);
    embA[((ks*16+rb)*64+lane)*8+j] = f2bf(e1);
  }
}

__global__ void k_init(int* __restrict__ upd, int C){
  int i = blockIdx.x*256 + threadIdx.x;
  if (i < C) upd[i] = -1;
}

// ---- virtual-prototype update ----
__global__ void k_vp(const float* __restrict__ queue, const float* __restrict__ emb,
                     const int* __restrict__ labels, float* __restrict__ newrow,
                     int* __restrict__ upd){
  int b = blockIdx.x, t = threadIdx.x;
  int lab = labels[b];
  const float* q = queue + (size_t)lab * D_DIM;
  float q0=q[t], q1=q[t+256];
  float e0=emb[b*D_DIM+t], e1=emb[b*D_DIM+256+t];
  __shared__ float red[256];
  __shared__ int win;
  red[t] = q0*e0 + q1*e1;
  __syncthreads();
  for (int o=128;o>0;o>>=1){ if(t<o) red[t]+=red[t+o]; __syncthreads(); }
  float drift = red[0];
  float fac = drift / (1.0f + fabsf(drift));
  float v0 = fac*q0 + (1.0f-fac)*e0;
  float v1 = fac*q1 + (1.0f-fac)*e1;
  __syncthreads();
  if (t==0) win = 1;
  red[t] = v0*v0 + v1*v1;
  __syncthreads();
  for (int o=128;o>0;o>>=1){ if(t<o) red[t]+=red[t+o]; __syncthreads(); }
  float inv = 1.0f / fmaxf(sqrtf(red[0]), 1e-12f);
  newrow[b*D_DIM+t]     = v0*inv;
  newrow[b*D_DIM+256+t] = v1*inv;
  if (t > b && labels[t] == lab) win = 0;
  __syncthreads();
  if (t==0 && win) upd[lab] = b;
}

// ---- fused double-GEMM: one-shot whole-row staging, barrier-free k-loop ----
// Block = 16 classes. Stage ALL 16 W rows + 16 Q rows (full 2KB contiguous
// rows, 1KB per gload16 inst) into 64KB LDS, ONE __syncthreads, then 16
// k-steps of pure LDS+MFMA with no barriers (waves free-run, compiler waits).
// Swizzle: within each 1KB half, lane l stores logical granule l^key
// (key=row&7); ds_read fetches granule (G^key) — involution, both-sides.
__global__ __launch_bounds__(256,2) void k_main(
    const float* __restrict__ W, const float* __restrict__ Q,
    const short* __restrict__ embA, const float* __restrict__ newrow,
    const int* __restrict__ upd, const int* __restrict__ labels,
    float* __restrict__ partials, float* __restrict__ posval,
    int C)
{
  __shared__ __align__(16) char ldsb[65536];      // [2 mats][16 rows][2048 B]
  const int wg   = blockIdx.x;
  const int tid  = threadIdx.x;
  const int wave = tid >> 6;
  const int lane = tid & 63;
  const int lcol = lane & 15;
  const int lkg  = lane >> 4;
  const int c0 = wg * NT;
  const int m0 = wave * 64;

  // ---- stage: wave w owns LDS rows [w*4, w*4+4) of both matrices ----
  {
    const float* wrow[4];
    const float* qrow[4];
#pragma unroll
    for (int ridx=0;ridx<4;ridx++){
      int r   = wave*4 + ridx;
      int cls = c0 + r;
      wrow[ridx] = W + (size_t)cls * D_DIM;
      int u = upd[cls];
      qrow[ridx] = (u >= 0) ? (newrow + (size_t)u * D_DIM) : (Q + (size_t)cls * D_DIM);
    }
#pragma unroll
    for (int t=0;t<8;t++){
      int ridx = t>>1, half = t&1;
      int r    = wave*4 + ridx;
      int key  = r & 7;
      gload16((const char*)wrow[ridx] + half*1024 + ((lane ^ key)<<4),
              ldsb + r*2048 + half*1024);
    }
#pragma unroll
    for (int t=0;t<8;t++){
      int ridx = t>>1, half = t&1;
      int r    = wave*4 + ridx;
      int key  = r & 7;
      gload16((const char*)qrow[ridx] + half*1024 + ((lane ^ key)<<4),
              ldsb + 32768 + r*2048 + half*1024);
    }
  }
  __syncthreads();   // vmcnt(0) + barrier: all 32 rows staged

  const short8* Af = reinterpret_cast<const short8*>(embA);
  const f32x4 vzero = {0.f,0.f,0.f,0.f};
  f32x4 accW[4], accQ[4], accNW, accNQ;
#pragma unroll
  for (int i=0;i<4;i++){ accW[i]=vzero; accQ[i]=vzero; }
  accNW=vzero; accNQ=vzero;

  const int key  = lcol & 7;
  const int rowb = lcol * 2048;

#pragma unroll
  for (int ks=0; ks<KSTEPS; ++ks){
    short8 a0 = Af[(ks*16 + wave*4 + 0)*64 + lane];
    short8 a1 = Af[(ks*16 + wave*4 + 1)*64 + lane];
    short8 a2 = Af[(ks*16 + wave*4 + 2)*64 + lane];
    short8 a3 = Af[(ks*16 + wave*4 + 3)*64 + lane];
    const int G0   = ks*8 + lkg*2;
    const int off0 = rowb + ((G0 ^ key)<<4);
    const int off1 = rowb + (((G0 ^ key) ^ 1)<<4);  // (G0+1)^key, G0 even
    const f32x4 w0 = *(const f32x4*)(ldsb + off0);
    const f32x4 w1 = *(const f32x4*)(ldsb + off1);
    const f32x4 z0 = *(const f32x4*)(ldsb + 32768 + off0);
    const f32x4 z1 = *(const f32x4*)(ldsb + 32768 + off1);
    short8 bw, bq;
#pragma unroll
    for (int j=0;j<4;j++){
      bw[j] = f2bf(w0[j]); bw[j+4] = f2bf(w1[j]);
      bq[j] = f2bf(z0[j]); bq[j+4] = f2bf(z1[j]);
    }
    // row norms on the matrix pipe (diag of Gram)
    accNW = __builtin_amdgcn_mfma_f32_16x16x32_bf16(bw, bw, accNW, 0, 0, 0);
    accNQ = __builtin_amdgcn_mfma_f32_16x16x32_bf16(bq, bq, accNQ, 0, 0, 0);
    accW[0] = __builtin_amdgcn_mfma_f32_16x16x32_bf16(a0, bw, accW[0], 0, 0, 0);
    accW[1] = __builtin_amdgcn_mfma_f32_16x16x32_bf16(a1, bw, accW[1], 0, 0, 0);
    accW[2] = __builtin_amdgcn_mfma_f32_16x16x32_bf16(a2, bw, accW[2], 0, 0, 0);
    accW[3] = __builtin_amdgcn_mfma_f32_16x16x32_bf16(a3, bw, accW[3], 0, 0, 0);
    accQ[0] = __builtin_amdgcn_mfma_f32_16x16x32_bf16(a0, bq, accQ[0], 0, 0, 0);
    accQ[1] = __builtin_amdgcn_mfma_f32_16x16x32_bf16(a1, bq, accQ[1], 0, 0, 0);
    accQ[2] = __builtin_amdgcn_mfma_f32_16x16x32_bf16(a2, bq, accQ[2], 0, 0, 0);
    accQ[3] = __builtin_amdgcn_mfma_f32_16x16x32_bf16(a3, bq, accQ[3], 0, 0, 0);
  }

  // column norms from Gram diagonals: diag col c lives on lane ((c>>2)<<4)|c, reg c&3
  float winv, qinv;
  {
    int rsel = lcol & 3;
    float vw = rsel==0?accNW[0]:rsel==1?accNW[1]:rsel==2?accNW[2]:accNW[3];
    float vq = rsel==0?accNQ[0]:rsel==1?accNQ[1]:rsel==2?accNQ[2]:accNQ[3];
    int src = ((lcol>>2)<<4) | lcol;
    float ssW = __shfl(vw, src);
    float ssQ = __shfl(vq, src);
    winv = 1.0f / fmaxf(sqrtf(ssW), 1e-5f);
    qinv = 1.0f / fmaxf(sqrtf(ssQ), 1e-12f);
  }

  // epilogue
#pragma unroll
  for (int rb=0;rb<4;rb++){
#pragma unroll
    for (int r=0;r<4;r++){
      const int m = m0 + rb*16 + lkg*4 + r;
      const int lab = labels[m];
      const int c = c0 + lcol;
      float nw = 0.f, nq = 0.f;
      {
        float cw = accW[rb][r] * winv;
        cw = fminf(fmaxf(cw, -1.0f + 1e-7f), 1.0f - 1e-7f);
        float cq = accQ[rb][r] * qinv;
        if (c == lab){
          float sw  = sqrtf(fminf(fmaxf(1.0f - cw*cw, 0.0f), 1.0f));
          float phw = cw*COS_M - sw*SIN_M;
          posval[m] = __expf(-S_SCALE*phw);
          float vq  = 0.3f * cq;
          float sq  = sqrtf(fminf(fmaxf(1.0f - vq*vq, 0.0f), 1.0f));
          float phq = vq*COS_M - sq*SIN_M;
          posval[NROWS + m] = __expf(-S_SCALE*phq);
        } else {
          nw = __expf(S_SCALE*cw);
          nq = __expf(S_SCALE*cq);
        }
      }
#pragma unroll
      for (int msk=1; msk<16; msk<<=1){
        nw += __shfl_xor(nw, msk);
        nq += __shfl_xor(nq, msk);
      }
      if (lcol == 0){
        partials[(size_t)wg*512 + m]       = nw;
        partials[(size_t)wg*512 + 256 + m] = nq;
      }
    }
  }
}

// ---- reduce partials per row (coalesced 16-column tiles), loss per row ----
__global__ void k_red(const float* __restrict__ partials, const float* __restrict__ posval,
                      float* __restrict__ lossv, int nwg){
  int n0 = blockIdx.x * 16;                       // 32 blocks x 256 threads
  int tx = threadIdx.x & 15, ty = threadIdx.x >> 4;
  float s = 0.f;
  for (int i=ty; i<nwg; i+=16) s += partials[(size_t)i*512 + n0 + tx];
  __shared__ float red[16][17];
  red[ty][tx] = s;
  __syncthreads();
  if (ty == 0){
    float acc = 0.f;
#pragma unroll
    for (int j=0;j<16;j++) acc += red[j][tx];
    int n = n0 + tx;
    lossv[n] = logf(1.0f + acc * posval[n]);
  }
}

__global__ void k_fin(const float* __restrict__ lossv, const int* __restrict__ epoch,
                      float* __restrict__ out){
  int t = threadIdx.x;
  int N = (epoch[0] + 1 >= 4) ? 2*NROWS : NROWS;
  float v = (t < N) ? lossv[t] : 0.f;
  __shared__ float red[512];
  red[t] = v; __syncthreads();
  for (int o=256;o>0;o>>=1){ if(t<o) red[t]+=red[t+o]; __syncthreads(); }
  if (t==0) out[0] = red[0] / (float)N;
}

extern "C" void kernel_launch(void* const* d_in, const int* in_sizes, int n_in,
                              void* d_out, int out_size, void* d_ws, size_t ws_size,
                              hipStream_t stream)
{
  const float* x      = (const float*)d_in[0];
  const int*   labels = (const int*)d_in[1];
  const float* W      = (const float*)d_in[2];
  const float* Q      = (const float*)d_in[3];
  const int*   epoch  = (const int*)d_in[4];
  float* out = (float*)d_out;
  const int C   = in_sizes[2] / D_DIM;            // 100000
  const int nwg = (C + NT - 1) / NT;              // 6250

  char* ws = (char*)d_ws;
  float* emb      = (float*)(ws + 0);             // 512 KB
  short* embA     = (short*)(ws + 524288);        // 256 KB
  float* newrow   = (float*)(ws + 786432);        // 512 KB
  int*   upd      = (int*)  (ws + 1310720);       // 400 KB
  float* posval   = (float*)(ws + 1712128);       // 2 KB
  float* lossv    = (float*)(ws + 1714176);       // 2 KB
  float* partials = (float*)(ws + 1716224);       // 512*nwg*4 B (~12.8 MB)

  hipLaunchKernelGGL(k_emb,  dim3(NROWS),       dim3(256), 0, stream, x, emb, embA);
  hipLaunchKernelGGL(k_init, dim3((C+255)/256), dim3(256), 0, stream, upd, C);
  hipLaunchKernelGGL(k_vp,   dim3(NROWS),       dim3(256), 0, stream, Q, emb, labels, newrow, upd);
  hipLaunchKernelGGL(k_main, dim3(nwg),         dim3(256), 0, stream,
                     W, Q, embA, newrow, upd, labels, partials, posval, C);
  hipLaunchKernelGGL(k_red,  dim3(32),          dim3(256), 0, stream, partials, posval, lossv, nwg);
  hipLaunchKernelGGL(k_fin,  dim3(1),           dim3(512), 0, stream, lossv, epoch, out);
}

// Round 7
// 269.816 us; speedup vs baseline: 1.2535x; 1.2535x over previous
//
#include <hip/hip_runtime.h>
#include <hip/hip_bf16.h>

#define D_DIM 512
#define NROWS 256
#define NT 16
#define KSTEPS 16
#define GRID 256
#define S_SCALE 64.0f
#define COS_M 0.9210609940028851f
#define SIN_M 0.3894183423086505f

typedef short short8 __attribute__((ext_vector_type(8)));
typedef float f32x4 __attribute__((ext_vector_type(4)));

typedef const __attribute__((address_space(1))) void* gas1_t;
typedef __attribute__((address_space(3))) void* las3_t;

static __device__ __forceinline__ void gload16(const void* g, void* l){
  __builtin_amdgcn_global_load_lds((gas1_t)g, (las3_t)l, 16, 0, 0);
}

static __device__ __forceinline__ short f2bf(float f){
  __hip_bfloat16 h = __float2bfloat16(f);
  return __builtin_bit_cast(short, h);
}

// ---- emb = l2norm(x, 1e-5); also pack A-fragments (bf16, fragment-major) ----
__global__ void k_emb(const float* __restrict__ x, float* __restrict__ emb,
                      short* __restrict__ embA){
  int b = blockIdx.x, t = threadIdx.x;            // 256 blocks x 256 threads
  float v0 = x[b*D_DIM + t];
  float v1 = x[b*D_DIM + 256 + t];
  __shared__ float red[256];
  red[t] = v0*v0 + v1*v1;
  __syncthreads();
  for (int o=128;o>0;o>>=1){ if(t<o) red[t]+=red[t+o]; __syncthreads(); }
  float inv = 1.0f / fmaxf(sqrtf(red[0]), 1e-5f);
  float e0 = v0*inv, e1 = v1*inv;
  emb[b*D_DIM + t]       = e0;
  emb[b*D_DIM + 256 + t] = e1;
  int rb = b >> 4;
  {
    int d=t; int ks=d>>5, kg=(d>>3)&3, j=d&7;
    int lane=(kg<<4)|(b&15);
    embA[((ks*16+rb)*64+lane)*8+j] = f2bf(e0);
  }
  {
    int d=t+256; int ks=d>>5, kg=(d>>3)&3, j=d&7;
    int lane=(kg<<4)|(b&15);
    embA[((ks*16+rb)*64+lane)*8+j] = f2bf(e1);
  }
}

__global__ void k_init(int* __restrict__ upd, int C){
  int i = blockIdx.x*256 + threadIdx.x;
  if (i < C) upd[i] = -1;
}

// ---- virtual-prototype update ----
__global__ void k_vp(const float* __restrict__ queue, const float* __restrict__ emb,
                     const int* __restrict__ labels, float* __restrict__ newrow,
                     int* __restrict__ upd){
  int b = blockIdx.x, t = threadIdx.x;
  int lab = labels[b];
  const float* q = queue + (size_t)lab * D_DIM;
  float q0=q[t], q1=q[t+256];
  float e0=emb[b*D_DIM+t], e1=emb[b*D_DIM+256+t];
  __shared__ float red[256];
  __shared__ int win;
  red[t] = q0*e0 + q1*e1;
  __syncthreads();
  for (int o=128;o>0;o>>=1){ if(t<o) red[t]+=red[t+o]; __syncthreads(); }
  float drift = red[0];
  float fac = drift / (1.0f + fabsf(drift));
  float v0 = fac*q0 + (1.0f-fac)*e0;
  float v1 = fac*q1 + (1.0f-fac)*e1;
  __syncthreads();
  if (t==0) win = 1;
  red[t] = v0*v0 + v1*v1;
  __syncthreads();
  for (int o=128;o>0;o>>=1){ if(t<o) red[t]+=red[t+o]; __syncthreads(); }
  float inv = 1.0f / fmaxf(sqrtf(red[0]), 1e-12f);
  newrow[b*D_DIM+t]     = v0*inv;
  newrow[b*D_DIM+256+t] = v1*inv;
  if (t > b && labels[t] == lab) win = 0;
  __syncthreads();
  if (t==0 && win) upd[lab] = b;
}

// ---- fused double-GEMM: persistent ping-pong whole-row streamer ----
// 256 persistent blocks (1/CU), 512 threads (8 waves). LDS = 2 slots x 32KB.
// Tile = 16 classes. Per tile: sync; issue Q(t)->slot1; compute W(slot0) and
// fill afr[16][2] reg-cache; sync; issue W(t+256)->slot0; compute Q(slot1)
// from afr; epilogue. Next-slot stage is ALWAYS in flight during compute.
// Swizzle (validated R6): store granule lane^key (key=row&7) from pre-swizzled
// global source; read granule G^key. Whole 2KB rows -> DRAM-friendly.
__global__ __launch_bounds__(512,2) void k_main(
    const float* __restrict__ W, const float* __restrict__ Q,
    const short* __restrict__ embA, const float* __restrict__ newrow,
    const int* __restrict__ upd, const int* __restrict__ labels,
    float* __restrict__ partials, float* __restrict__ posval,
    int C, int ntiles)
{
  __shared__ __align__(16) char ldsb[65536];      // [2 slots][16 rows][2048]
  const int bid  = blockIdx.x;
  const int tid  = threadIdx.x;
  const int wave = tid >> 6;                      // 0..7
  const int lane = tid & 63;
  const int lcol = lane & 15;
  const int lkg  = lane >> 4;

  // staging: wave stages rows r0=wave*2, r1=wave*2+1 of each matrix (2KB rows)
  const int r0 = wave*2, r1 = wave*2 + 1;
  const int sw0 = ((lane ^ (r0 & 7)) << 4);       // pre-swizzled source offset
  const int sw1 = ((lane ^ (r1 & 7)) << 4);

  // hoisted labels for this wave's 32 rows
  int labr[2][4];
#pragma unroll
  for (int rb=0;rb<2;rb++)
#pragma unroll
    for (int r=0;r<4;r++)
      labr[rb][r] = labels[wave*32 + rb*16 + lkg*4 + r];

  const short8* Af = reinterpret_cast<const short8*>(embA);
  // ds_read bases: addr = lcol*2048 + (ks*8 + ((lkg*2)^key))*16, key=lcol&7
  const int key  = lcol & 7;
  const int dsb0 = lcol*2048 + (((lkg*2) ^ key) << 4);
  const int dsb1 = dsb0 ^ 16;

  const f32x4 vzero = {0.f,0.f,0.f,0.f};
  f32x4 accW[2], accQ[2], accNW, accNQ;
  accW[0]=vzero; accW[1]=vzero; accQ[0]=vzero; accQ[1]=vzero;
  accNW=vzero; accNQ=vzero;

  short8 afr[16][2];                              // A-frag reg cache (128 VGPR)

  int t = bid;
  // prologue: upd for tile t; stage W(t) -> slot0
  int updc0 = upd[t*16 + r0];
  int updc1 = upd[t*16 + r1];
  {
    const char* w0p = (const char*)(W + (size_t)(t*16 + r0) * D_DIM);
    const char* w1p = (const char*)(W + (size_t)(t*16 + r1) * D_DIM);
    gload16(w0p + sw0,        ldsb + r0*2048);
    gload16(w0p + 1024 + sw0, ldsb + r0*2048 + 1024);
    gload16(w1p + sw1,        ldsb + r1*2048);
    gload16(w1p + 1024 + sw1, ldsb + r1*2048 + 1024);
  }

  for (; t < ntiles; t += GRID){
    const int tn = t + GRID;
    // ================= W-slot =================
    __syncthreads();                              // W(t) ready in slot0
    // issue Q(t) stage -> slot1 (in flight during W-compute)
    {
      const float* q0p = (updc0 >= 0) ? (newrow + (size_t)updc0 * D_DIM)
                                      : (Q + (size_t)(t*16 + r0) * D_DIM);
      const float* q1p = (updc1 >= 0) ? (newrow + (size_t)updc1 * D_DIM)
                                      : (Q + (size_t)(t*16 + r1) * D_DIM);
      gload16((const char*)q0p + sw0,        ldsb + 32768 + r0*2048);
      gload16((const char*)q0p + 1024 + sw0, ldsb + 32768 + r0*2048 + 1024);
      gload16((const char*)q1p + sw1,        ldsb + 32768 + r1*2048);
      gload16((const char*)q1p + 1024 + sw1, ldsb + 32768 + r1*2048 + 1024);
    }
    __builtin_amdgcn_sched_barrier(0);
    // prefetch upd for next tile (consumed at next W-slot)
    int updn0 = -1, updn1 = -1;
    if (tn < ntiles){ updn0 = upd[tn*16 + r0]; updn1 = upd[tn*16 + r1]; }

#pragma unroll
    for (int ks=0; ks<KSTEPS; ++ks){
      afr[ks][0] = Af[(ks*16 + wave*2 + 0)*64 + lane];
      afr[ks][1] = Af[(ks*16 + wave*2 + 1)*64 + lane];
      const f32x4 w0 = *(const f32x4*)(ldsb + dsb0 + ks*128);
      const f32x4 w1 = *(const f32x4*)(ldsb + dsb1 + ks*128);
      short8 bw;
#pragma unroll
      for (int j=0;j<4;j++){ bw[j] = f2bf(w0[j]); bw[j+4] = f2bf(w1[j]); }
      accNW   = __builtin_amdgcn_mfma_f32_16x16x32_bf16(bw, bw, accNW, 0, 0, 0);
      accW[0] = __builtin_amdgcn_mfma_f32_16x16x32_bf16(afr[ks][0], bw, accW[0], 0, 0, 0);
      accW[1] = __builtin_amdgcn_mfma_f32_16x16x32_bf16(afr[ks][1], bw, accW[1], 0, 0, 0);
    }

    // ================= Q-slot =================
    __syncthreads();                              // Q(t) ready in slot1
    if (tn < ntiles){                             // issue W(tn) -> slot0
      const char* w0p = (const char*)(W + (size_t)(tn*16 + r0) * D_DIM);
      const char* w1p = (const char*)(W + (size_t)(tn*16 + r1) * D_DIM);
      gload16(w0p + sw0,        ldsb + r0*2048);
      gload16(w0p + 1024 + sw0, ldsb + r0*2048 + 1024);
      gload16(w1p + sw1,        ldsb + r1*2048);
      gload16(w1p + 1024 + sw1, ldsb + r1*2048 + 1024);
    }
    __builtin_amdgcn_sched_barrier(0);

#pragma unroll
    for (int ks=0; ks<KSTEPS; ++ks){
      const f32x4 z0 = *(const f32x4*)(ldsb + 32768 + dsb0 + ks*128);
      const f32x4 z1 = *(const f32x4*)(ldsb + 32768 + dsb1 + ks*128);
      short8 bq;
#pragma unroll
      for (int j=0;j<4;j++){ bq[j] = f2bf(z0[j]); bq[j+4] = f2bf(z1[j]); }
      accNQ   = __builtin_amdgcn_mfma_f32_16x16x32_bf16(bq, bq, accNQ, 0, 0, 0);
      accQ[0] = __builtin_amdgcn_mfma_f32_16x16x32_bf16(afr[ks][0], bq, accQ[0], 0, 0, 0);
      accQ[1] = __builtin_amdgcn_mfma_f32_16x16x32_bf16(afr[ks][1], bq, accQ[1], 0, 0, 0);
    }

    // ================= epilogue (tile t) =================
    float winv, qinv;
    {
      int rsel = lcol & 3;
      float vw = rsel==0?accNW[0]:rsel==1?accNW[1]:rsel==2?accNW[2]:accNW[3];
      float vq = rsel==0?accNQ[0]:rsel==1?accNQ[1]:rsel==2?accNQ[2]:accNQ[3];
      int src = ((lcol>>2)<<4) | lcol;            // diag col c on lane ((c>>2)<<4)|c
      float ssW = __shfl(vw, src);
      float ssQ = __shfl(vq, src);
      winv = 1.0f / fmaxf(sqrtf(ssW), 1e-5f);
      qinv = 1.0f / fmaxf(sqrtf(ssQ), 1e-12f);
    }
    const int c = t*16 + lcol;
#pragma unroll
    for (int rb=0;rb<2;rb++){
#pragma unroll
      for (int r=0;r<4;r++){
        const int m = wave*32 + rb*16 + lkg*4 + r;
        const int lab = labr[rb][r];
        float nw = 0.f, nq = 0.f;
        {
          float cw = accW[rb][r] * winv;
          cw = fminf(fmaxf(cw, -1.0f + 1e-7f), 1.0f - 1e-7f);
          float cq = accQ[rb][r] * qinv;
          if (c == lab){
            float sw  = sqrtf(fminf(fmaxf(1.0f - cw*cw, 0.0f), 1.0f));
            float phw = cw*COS_M - sw*SIN_M;
            posval[m] = __expf(-S_SCALE*phw);
            float vq  = 0.3f * cq;
            float sq  = sqrtf(fminf(fmaxf(1.0f - vq*vq, 0.0f), 1.0f));
            float phq = vq*COS_M - sq*SIN_M;
            posval[NROWS + m] = __expf(-S_SCALE*phq);
          } else {
            nw = __expf(S_SCALE*cw);
            nq = __expf(S_SCALE*cq);
          }
        }
#pragma unroll
        for (int msk=1; msk<16; msk<<=1){
          nw += __shfl_xor(nw, msk);
          nq += __shfl_xor(nq, msk);
        }
        if (lcol == 0){
          partials[(size_t)t*512 + m]       = nw;
          partials[(size_t)t*512 + 256 + m] = nq;
        }
      }
    }
    // rotate state
    updc0 = updn0; updc1 = updn1;
    accW[0]=vzero; accW[1]=vzero; accQ[0]=vzero; accQ[1]=vzero;
    accNW=vzero; accNQ=vzero;
  }
}

// ---- reduce partials per row (coalesced 16-column tiles), loss per row ----
__global__ void k_red(const float* __restrict__ partials, const float* __restrict__ posval,
                      float* __restrict__ lossv, int nwg){
  int n0 = blockIdx.x * 16;                       // 32 blocks x 256 threads
  int tx = threadIdx.x & 15, ty = threadIdx.x >> 4;
  float s = 0.f;
  for (int i=ty; i<nwg; i+=16) s += partials[(size_t)i*512 + n0 + tx];
  __shared__ float red[16][17];
  red[ty][tx] = s;
  __syncthreads();
  if (ty == 0){
    float acc = 0.f;
#pragma unroll
    for (int j=0;j<16;j++) acc += red[j][tx];
    int n = n0 + tx;
    lossv[n] = logf(1.0f + acc * posval[n]);
  }
}

__global__ void k_fin(const float* __restrict__ lossv, const int* __restrict__ epoch,
                      float* __restrict__ out){
  int t = threadIdx.x;
  int N = (epoch[0] + 1 >= 4) ? 2*NROWS : NROWS;
  float v = (t < N) ? lossv[t] : 0.f;
  __shared__ float red[512];
  red[t] = v; __syncthreads();
  for (int o=256;o>0;o>>=1){ if(t<o) red[t]+=red[t+o]; __syncthreads(); }
  if (t==0) out[0] = red[0] / (float)N;
}

extern "C" void kernel_launch(void* const* d_in, const int* in_sizes, int n_in,
                              void* d_out, int out_size, void* d_ws, size_t ws_size,
                              hipStream_t stream)
{
  const float* x      = (const float*)d_in[0];
  const int*   labels = (const int*)d_in[1];
  const float* W      = (const float*)d_in[2];
  const float* Q      = (const float*)d_in[3];
  const int*   epoch  = (const int*)d_in[4];
  float* out = (float*)d_out;
  const int C      = in_sizes[2] / D_DIM;         // 100000
  const int ntiles = (C + NT - 1) / NT;           // 6250

  char* ws = (char*)d_ws;
  float* emb      = (float*)(ws + 0);             // 512 KB
  short* embA     = (short*)(ws + 524288);        // 256 KB
  float* newrow   = (float*)(ws + 786432);        // 512 KB
  int*   upd      = (int*)  (ws + 1310720);       // 400 KB
  float* posval   = (float*)(ws + 1712128);       // 2 KB
  float* lossv    = (float*)(ws + 1714176);       // 2 KB
  float* partials = (float*)(ws + 1716224);       // 512*ntiles*4 B (~12.8 MB)

  hipLaunchKernelGGL(k_emb,  dim3(NROWS),       dim3(256), 0, stream, x, emb, embA);
  hipLaunchKernelGGL(k_init, dim3((C+255)/256), dim3(256), 0, stream, upd, C);
  hipLaunchKernelGGL(k_vp,   dim3(NROWS),       dim3(256), 0, stream, Q, emb, labels, newrow, upd);
  hipLaunchKernelGGL(k_main, dim3(GRID),        dim3(512), 0, stream,
                     W, Q, embA, newrow, upd, labels, partials, posval, C, ntiles);
  hipLaunchKernelGGL(k_red,  dim3(32),          dim3(256), 0, stream, partials, posval, lossv, ntiles);
  hipLaunchKernelGGL(k_fin,  dim3(1),           dim3(512), 0, stream, lossv, epoch, out);
}